// Round 5
// baseline (338.743 us; speedup 1.0000x reference)
//
#include <hip/hip_runtime.h>

#define HWc   262144   // 512*512
#define CGc   128
#define CHc   64
#define COc   32
#define NPIXc 524288   // B*H*W
#define TW 32
#define TH 8
#define HLW 38         // TW+6
#define HLH 14         // TH+6
#define HPX (HLW*HLH)  // 532

typedef _Float16 h2 __attribute__((ext_vector_type(2)));

__device__ __forceinline__ int refl(int p){
  if (p < 0) p = -p;
  else if (p >= 512) p = 1022 - p;
  return p;
}
__device__ __forceinline__ h2 as_h2(unsigned u){ union{unsigned u; h2 h;} x; x.u = u; return x.h; }
__device__ __forceinline__ unsigned as_u(h2 h){ union{unsigned u; h2 h;} x; x.h = h; return x.u; }
__device__ __forceinline__ unsigned pkh(float a, float b){
  h2 h; h.x = (_Float16)a; h.y = (_Float16)b; return as_u(h);
}
__device__ __forceinline__ float2 upk(unsigned u){
  h2 h = as_h2(u); return make_float2((float)h.x, (float)h.y);
}
// d = a.f16[0]*b.f16[0] + a.f16[1]*b.f16[1] + c   (v_dot2_f32_f16)
__device__ __forceinline__ float dot2h(unsigned a, unsigned b, float c){
  return __builtin_amdgcn_fdot2(as_h2(a), as_h2(b), c, false);
}
// acc += f16half(ab) * e   — one VOP3P v_fma_mix_f32, no unpack (identical math to cvt+fma)
__device__ __forceinline__ void mixlo(float& acc, unsigned ab, float e){
  asm("v_fma_mix_f32 %0, %1, %2, %0 op_sel:[0,0,0] op_sel_hi:[1,0,0]"
      : "+v"(acc) : "v"(ab), "v"(e));
}
__device__ __forceinline__ void mixhi(float& acc, unsigned ab, float e){
  asm("v_fma_mix_f32 %0, %1, %2, %0 op_sel:[1,0,0] op_sel_hi:[1,0,0]"
      : "+v"(acc) : "v"(ab), "v"(e));
}

// -------- K0: sigma, pack w_sn and wg to f16 pairs -----------------------------------
__global__ void k0_prep(const float* __restrict__ wbar, const float* __restrict__ u,
                        const float* __restrict__ wg,
                        unsigned* __restrict__ wsnb, unsigned* __restrict__ wgb){
  const int t = threadIdx.x;
  __shared__ float sv1[32];
  float tv = 0.f;
  if (t < 32){
    #pragma unroll
    for (int o = 0; o < 32; o++) tv += wbar[o*32 + t] * u[o];
  }
  float sq = tv * tv;
  #pragma unroll
  for (int off = 32; off; off >>= 1) sq += __shfl_down(sq, off);
  const float n1 = sqrtf(__shfl(sq, 0)) + 1e-12f;
  if (t < 32) sv1[t] = tv / n1;
  __syncthreads();
  float tu = 0.f;
  if (t < 32){
    #pragma unroll
    for (int c = 0; c < 32; c++) tu += wbar[t*32 + c] * sv1[c];
  }
  float sq2 = tu * tu;
  #pragma unroll
  for (int off = 32; off; off >>= 1) sq2 += __shfl_down(sq2, off);
  const float S = __shfl(sq2, 0);
  const float inv = (sqrtf(S) + 1e-12f) / S;     // 1/sigma
  for (int k = t; k < 512; k += 64){             // wsnb[o][p], 16 pairs per row
    const int o = k >> 4, p = k & 15;
    wsnb[k] = pkh(wbar[o*32 + 2*p] * inv, wbar[o*32 + 2*p + 1] * inv);
  }
  for (int k = t; k < 4096; k += 64){            // wgb[o][p], 64 pairs per row
    const int o = k >> 6, p = k & 63;
    wgb[k] = pkh(wg[o*128 + 2*p], wg[o*128 + 2*p + 1]);
  }
}

// -------- K1f: fused {1x1 conv 128->64 + L2 norm -> gn}  and  {alpha' = W_sn*alpha} --
__global__ __launch_bounds__(256) void k1f(const float* __restrict__ f,
                                           const float* __restrict__ alpha,
                                           const unsigned* __restrict__ wgb,
                                           const unsigned* __restrict__ wsnb,
                                           const float* __restrict__ bg,
                                           unsigned* __restrict__ gn,
                                           unsigned* __restrict__ apm){
  const int p   = blockIdx.x * 256 + threadIdx.x;
  const int b   = p >> 18;
  const int pix = p & (HWc - 1);
  const float* fb = f + (size_t)b * CGc * HWc + pix;

  // ---- gn = normalize(Wg f + bg) ----
  float acc[CHc];
  #pragma unroll
  for (int o = 0; o < CHc; o++) acc[o] = bg[o];

  #pragma unroll 1
  for (int pp = 0; pp < 64; pp += 4){
    unsigned fp[4];
    #pragma unroll
    for (int m = 0; m < 4; m++)
      fp[m] = pkh(fb[(size_t)(2*(pp+m)) * HWc], fb[(size_t)(2*(pp+m)+1) * HWc]);
    #pragma unroll
    for (int o = 0; o < CHc; o++){
      float a = acc[o];
      a = dot2h(fp[0], wgb[o*64 + pp + 0], a);
      a = dot2h(fp[1], wgb[o*64 + pp + 1], a);
      a = dot2h(fp[2], wgb[o*64 + pp + 2], a);
      a = dot2h(fp[3], wgb[o*64 + pp + 3], a);
      acc[o] = a;
    }
  }
  float nsq = 0.f;
  #pragma unroll
  for (int o = 0; o < CHc; o++) nsq = fmaf(acc[o], acc[o], nsq);
  const float inv = 1.f / fmaxf(sqrtf(nsq), 1e-4f);

  uint4* gp = (uint4*)(gn + (size_t)p * 32);
  #pragma unroll
  for (int k = 0; k < 8; k++){
    uint4 w;
    w.x = pkh(acc[8*k+0]*inv, acc[8*k+1]*inv);
    w.y = pkh(acc[8*k+2]*inv, acc[8*k+3]*inv);
    w.z = pkh(acc[8*k+4]*inv, acc[8*k+5]*inv);
    w.w = pkh(acc[8*k+6]*inv, acc[8*k+7]*inv);
    gp[k] = w;
  }

  // ---- apm = f16(W_sn * alpha), pixel-major ----
  const float* ab = alpha + (size_t)b * COc * HWc + pix;
  unsigned a16[16];
  #pragma unroll
  for (int k = 0; k < 16; k++)
    a16[k] = pkh(ab[(size_t)(2*k) * HWc], ab[(size_t)(2*k+1) * HWc]);
  unsigned ow[16];
  #pragma unroll
  for (int o = 0; o < COc; o += 2){
    float s0 = 0.f, s1 = 0.f;
    #pragma unroll
    for (int k = 0; k < 16; k++){
      s0 = dot2h(a16[k], wsnb[(o+0)*16 + k], s0);
      s1 = dot2h(a16[k], wsnb[(o+1)*16 + k], s1);
    }
    ow[o >> 1] = pkh(s0, s1);
  }
  uint4* op = (uint4*)(apm + (size_t)p * 16);
  #pragma unroll
  for (int k = 0; k < 4; k++)
    op[k] = make_uint4(ow[4*k], ow[4*k+1], ow[4*k+2], ow[4*k+3]);
}

// -------- K2: correlation + softmax + agg (fma_mix) -> y2 f16, + fused BN stats ------
__global__ __launch_bounds__(256) void k2_agg(const unsigned* __restrict__ gn,
                                              const unsigned* __restrict__ apm,
                                              unsigned* __restrict__ y2,
                                              float* __restrict__ stats){
  __shared__ uint4 gs4[8][HPX];   // 8 channel-pair planes, lane-contiguous 16B
  __shared__ float red[4][64];

  const int lb  = (blockIdx.x & 7) * 256 + (blockIdx.x >> 3);   // XCD-chunked swizzle
  const int txx = lb & 15;
  const int tyy = (lb >> 4) & 63;
  const int bb  = lb >> 10;
  const int x0  = txx * TW, y0 = tyy * TH;
  const int tid = threadIdx.x;

  for (int t = tid; t < HPX; t += 256){
    const int hr = t / HLW;
    const int hc = t - hr * HLW;
    const int gy = refl(y0 + hr - 3);
    const int gx = refl(x0 + hc - 3);
    const uint4* src = (const uint4*)(gn + (size_t)((bb << 18) + (gy << 9) + gx) * 32);
    #pragma unroll
    for (int k = 0; k < 8; k++) gs4[k][t] = src[k];
  }
  __syncthreads();

  const int r  = tid >> 5, c = tid & 31;
  const int yy = y0 + r,  xx = x0 + c;
  const int self = (r + 3) * HLW + (c + 3);

  uint4 cv[8];
  #pragma unroll
  for (int k = 0; k < 8; k++) cv[k] = gs4[k][self];

  int ax[7];
  #pragma unroll
  for (int j = 0; j < 7; j++) ax[j] = refl(xx + j - 3);

  float yac[COc];
  #pragma unroll
  for (int k = 0; k < COc; k++) yac[k] = 0.f;
  float esum = 0.f;

  #pragma unroll 1
  for (int i = 0; i < 7; i++){
    const int ay = refl(yy + i - 3);
    const unsigned* aprow = apm + (size_t)((bb << 18) + (ay << 9)) * 16;
    const int rowbase = (r + i) * HLW + c;
    #pragma unroll
    for (int j = 0; j < 7; j++){
      if (i == 3 && j == 3) continue;          // center tap: exp(-10000) == 0
      const int hp = rowbase + j;
      float s0 = 0.f, s1 = 0.f, s2 = 0.f, s3 = 0.f;
      #pragma unroll
      for (int k = 0; k < 8; k++){
        const uint4 q = gs4[k][hp];
        s0 = dot2h(cv[k].x, q.x, s0);
        s1 = dot2h(cv[k].y, q.y, s1);
        s2 = dot2h(cv[k].z, q.z, s2);
        s3 = dot2h(cv[k].w, q.w, s3);
      }
      // |s|<=~1 (unit vectors): exp(s) directly == softmax with max folded out
      const float e = __expf((s0 + s1) + (s2 + s3));
      esum += e;
      const uint4* ap = (const uint4*)(aprow + (size_t)ax[j] * 16);
      #pragma unroll
      for (int kk = 0; kk < 4; kk++){
        const uint4 a = ap[kk];
        mixlo(yac[8*kk+0], a.x, e); mixhi(yac[8*kk+1], a.x, e);
        mixlo(yac[8*kk+2], a.y, e); mixhi(yac[8*kk+3], a.y, e);
        mixlo(yac[8*kk+4], a.z, e); mixhi(yac[8*kk+5], a.z, e);
        mixlo(yac[8*kk+6], a.w, e); mixhi(yac[8*kk+7], a.w, e);
      }
    }
  }

  const float inv = 1.f / esum;
  float yn[COc];
  unsigned yw[16];
  #pragma unroll
  for (int k = 0; k < 16; k++){
    yn[2*k]   = yac[2*k]   * inv;
    yn[2*k+1] = yac[2*k+1] * inv;
    yw[k] = pkh(yn[2*k], yn[2*k+1]);
  }
  uint4* yp = (uint4*)(y2 + (size_t)((bb << 18) + (yy << 9) + xx) * 16);
  #pragma unroll
  for (int k = 0; k < 4; k++)
    yp[k] = make_uint4(yw[4*k], yw[4*k+1], yw[4*k+2], yw[4*k+3]);

  // ---- fused BN stats: per-wave shuffle reduce -> LDS -> 64 atomics per block ----
  float sch[COc], qch[COc];
  #pragma unroll
  for (int o = 0; o < COc; o++){ sch[o] = yn[o]; qch[o] = yn[o] * yn[o]; }
  #pragma unroll
  for (int o = 0; o < COc; o++){
    #pragma unroll
    for (int off = 32; off; off >>= 1){
      sch[o] += __shfl_down(sch[o], off);
      qch[o] += __shfl_down(qch[o], off);
    }
  }
  const int wv = tid >> 6;
  if ((tid & 63) == 0){
    #pragma unroll
    for (int o = 0; o < COc; o++){ red[wv][o] = sch[o]; red[wv][32 + o] = qch[o]; }
  }
  __syncthreads();
  if (tid < 64){
    atomicAdd(&stats[tid], red[0][tid] + red[1][tid] + red[2][tid] + red[3][tid]);
  }
}

// -------- K3b: stats -> (mean, 0.1*rsqrt(var+eps)) ------------------------------------
__global__ void k3b_final(const float* __restrict__ stats, float* __restrict__ stats2){
  const int t = threadIdx.x;
  if (t < COc){
    const float invN = 1.f / (float)NPIXc;
    const float mean = stats[t] * invN;
    const float var  = fmaf(-mean, mean, stats[COc + t] * invN);
    stats2[t]       = mean;
    stats2[COc + t] = 0.1f * rsqrtf(var + 1e-5f);
  }
}

// -------- K4: BatchNorm + residual ----------------------------------------------------
__global__ __launch_bounds__(256) void k4_out(const unsigned* __restrict__ y2,
                                              const float* __restrict__ alpha,
                                              const float* __restrict__ stats2,
                                              float* __restrict__ out){
  const int p   = blockIdx.x * 256 + threadIdx.x;
  const int b   = p >> 18;
  const int pix = p & (HWc - 1);
  const uint4* yp = (const uint4*)(y2 + (size_t)p * 16);
  const size_t boff = (size_t)b * COc * HWc + pix;
  #pragma unroll
  for (int k = 0; k < 4; k++){
    const uint4 w = yp[k];
    const unsigned vv[4] = {w.x, w.y, w.z, w.w};
    #pragma unroll
    for (int m = 0; m < 4; m++){
      const int o = 8*k + 2*m;
      const float2 ab = upk(vv[m]);
      out[boff + (size_t)o*HWc]     = fmaf(ab.x - stats2[o],   stats2[COc+o],
                                           alpha[boff + (size_t)o*HWc]);
      out[boff + (size_t)(o+1)*HWc] = fmaf(ab.y - stats2[o+1], stats2[COc+o+1],
                                           alpha[boff + (size_t)(o+1)*HWc]);
    }
  }
}

extern "C" void kernel_launch(void* const* d_in, const int* in_sizes, int n_in,
                              void* d_out, int out_size, void* d_ws, size_t ws_size,
                              hipStream_t stream){
  const float* f     = (const float*)d_in[0];
  const float* alpha = (const float*)d_in[1];
  const float* wg    = (const float*)d_in[2];
  const float* bg    = (const float*)d_in[3];
  const float* wbar  = (const float*)d_in[4];
  const float* u     = (const float*)d_in[5];
  (void)in_sizes; (void)n_in; (void)out_size; (void)ws_size;
  float* out = (float*)d_out;

  char* ws = (char*)d_ws;
  float*    stats  = (float*)ws;                       // 256 B
  float*    stats2 = (float*)(ws + 4096);              // 256 B
  unsigned* wsnb   = (unsigned*)(ws + 8192);           // 2 KB
  unsigned* wgb    = (unsigned*)(ws + 16384);          // 16 KB
  unsigned* apm    = (unsigned*)(ws + 65536);                                   // 32 MB
  unsigned* gn     = (unsigned*)(ws + 65536 + (size_t)NPIXc*64);                // 64 MB
  unsigned* y2     = (unsigned*)(ws + 65536 + (size_t)NPIXc*64 + (size_t)NPIXc*128); // 32 MB

  hipMemsetAsync(stats, 0, 64 * sizeof(float), stream);
  k0_prep  <<<1, 64, 0, stream>>>(wbar, u, wg, wsnb, wgb);
  k1f      <<<NPIXc / 256, 256, 0, stream>>>(f, alpha, wgb, wsnb, bg, gn, apm);
  k2_agg   <<<2048, 256, 0, stream>>>(gn, apm, y2, stats);
  k3b_final<<<1, 64, 0, stream>>>(stats, stats2);
  k4_out   <<<NPIXc / 256, 256, 0, stream>>>(y2, alpha, stats2, out);
}